// Round 1
// baseline (217.716 us; speedup 1.0000x reference)
//
#include <hip/hip_runtime.h>

#define NCH 30      // channels per cell
#define CPB 256     // cells per block
#define TPB 256     // threads per block

__device__ __forceinline__ float iou_f(float x1, float y1, float w1, float h1,
                                       float x2, float y2, float w2, float h2) {
    float l1 = x1 - 0.5f * w1, r1 = x1 + 0.5f * w1;
    float t1 = y1 - 0.5f * h1, b1 = y1 + 0.5f * h1;
    float l2 = x2 - 0.5f * w2, r2 = x2 + 0.5f * w2;
    float t2 = y2 - 0.5f * h2, b2 = y2 + 0.5f * h2;
    float in_h = fminf(b1, b2) - fmaxf(t1, t2);
    float in_w = fminf(r1, r2) - fmaxf(l1, l2);
    float inter = (in_h < 0.f || in_w < 0.f) ? 0.f : in_h * in_w;
    float a1 = (b1 - t1) * (r1 - l1);
    float a2 = (b2 - t2) * (r2 - l2);
    return inter / (a1 + a2 - inter);
}

__global__ __launch_bounds__(TPB) void yolo_loss(const float* __restrict__ pred,
                                                 const float* __restrict__ lab,
                                                 float* __restrict__ out,
                                                 int n_cells) {
    __shared__ float s_p[CPB * NCH];
    __shared__ float s_l[CPB * NCH];
    __shared__ float red[5][TPB / 64];

    const int tid = threadIdx.x;
    const size_t cell0 = (size_t)blockIdx.x * CPB;
    const size_t base = cell0 * NCH;
    const size_t total = (size_t)n_cells * NCH;

    // ---- Stage global -> LDS with coalesced float4 loads ----
    const float4* gp = (const float4*)(pred + base);
    const float4* gl = (const float4*)(lab + base);
    float4* sp = (float4*)s_p;
    float4* sl = (float4*)s_l;
    const int nvec = CPB * NCH / 4;                       // 1920 float4 per array
    const size_t avail = (total > base) ? (total - base) : 0;
    const int nv = (int)((avail / 4) < (size_t)nvec ? (avail / 4) : (size_t)nvec);
    for (int i = tid; i < nv; i += TPB) {
        sp[i] = gp[i];
        sl[i] = gl[i];
    }
    __syncthreads();

    // ---- Per-cell compute ----
    float v0 = 0.f, v1 = 0.f, v2 = 0.f, v3 = 0.f, v4 = 0.f;
    if (cell0 + (size_t)tid < (size_t)n_cells) {
        const float* cp = s_p + tid * NCH;
        const float* cl = s_l + tid * NCH;
        float mask = cl[0];
        float gx = cl[1], gy = cl[2], gw = cl[3], gh = cl[4];

        float i1 = iou_f(cp[1], cp[2], cp[3], cp[4], gx, gy, gw, gh);
        float i2 = iou_f(cp[6], cp[7], cp[8], cp[9], gx, gy, gw, gh);
        bool best = (i1 >= i2);
        float sx = best ? cp[1] : cp[6];
        float sy = best ? cp[2] : cp[7];
        float sw = best ? cp[3] : cp[8];
        float sh = best ? cp[4] : cp[9];
        float imax = best ? i1 : i2;
        float imin = best ? i2 : i1;

        float center = 5.f * ((sx - gx) * (sx - gx) + (sy - gy) * (sy - gy));
        float dw = sqrtf(sw) - sqrtf(gw);
        float dh = sqrtf(sh) - sqrtf(gh);
        float wh = 5.f * (dw * dw + dh * dh);

        float cls = 0.f;
#pragma unroll
        for (int c = 10; c < 30; ++c) {
            float d = cp[c] - cl[c];
            cls += d * d;
        }

        v0 = center * mask;
        v1 = wh * mask;
        v2 = imax * mask;
        v3 = imin * mask;
        v4 = cls * mask;
    }

    // ---- Wave (64-lane) shuffle reduction ----
#pragma unroll
    for (int off = 32; off > 0; off >>= 1) {
        v0 += __shfl_down(v0, off);
        v1 += __shfl_down(v1, off);
        v2 += __shfl_down(v2, off);
        v3 += __shfl_down(v3, off);
        v4 += __shfl_down(v4, off);
    }

    const int wave = tid >> 6;
    const int lane = tid & 63;
    if (lane == 0) {
        red[0][wave] = v0;
        red[1][wave] = v1;
        red[2][wave] = v2;
        red[3][wave] = v3;
        red[4][wave] = v4;
    }
    __syncthreads();

    if (tid < 5) {
        float s = 0.f;
#pragma unroll
        for (int w = 0; w < TPB / 64; ++w) s += red[tid][w];
        atomicAdd(&out[tid], s);
    }
}

extern "C" void kernel_launch(void* const* d_in, const int* in_sizes, int n_in,
                              void* d_out, int out_size, void* d_ws, size_t ws_size,
                              hipStream_t stream) {
    const float* pred = (const float*)d_in[0];
    const float* lab  = (const float*)d_in[1];
    float* out = (float*)d_out;

    const int n_cells = in_sizes[0] / NCH;   // 16384*7*7 = 802816
    const int grid = (n_cells + CPB - 1) / CPB;

    hipMemsetAsync(d_out, 0, out_size * sizeof(float), stream);
    hipLaunchKernelGGL(yolo_loss, dim3(grid), dim3(TPB), 0, stream,
                       pred, lab, out, n_cells);
}